// Round 1
// baseline (84.659 us; speedup 1.0000x reference)
//
#include <hip/hip_runtime.h>

#define B_ 2048
#define S_ 512
#define T_ 17

// One step of the scaled forward recurrence + fused score accumulation.
// UU: compile-time phase (renorm when UU%4==0). tt: runtime step index.
#define CRF_STEP(UU, tt, LG, TG, MI) do {                                        \
    const float4* wv_ = (const float4*)(&wbuf[g][0]);                            \
    float4 a0_ = wv_[0], a1_ = wv_[1], a2_ = wv_[2], a3_ = wv_[3];               \
    float a16_ = wbuf[g][16];                                                    \
    __builtin_amdgcn_wave_barrier();                                             \
    float s0_ = fmaf(a0_.x, Ec[0], fmaf(a0_.y, Ec[1], fmaf(a0_.z, Ec[2],  a0_.w*Ec[3])));  \
    float s1_ = fmaf(a1_.x, Ec[4], fmaf(a1_.y, Ec[5], fmaf(a1_.z, Ec[6],  a1_.w*Ec[7])));  \
    float s2_ = fmaf(a2_.x, Ec[8], fmaf(a2_.y, Ec[9], fmaf(a2_.z, Ec[10], a2_.w*Ec[11]))); \
    float s3_ = fmaf(a3_.x, Ec[12],fmaf(a3_.y, Ec[13],fmaf(a3_.z, Ec[14], a3_.w*Ec[15]))); \
    float s_ = ((s0_ + s1_) + (s2_ + s3_)) + a16_ * Ec[16];                      \
    float r_ = 1.0f;                                                             \
    if (((UU) & 3) == 0) {                                                       \
        float M_ = fmaxf(fmaxf(fmaxf(a0_.x,a0_.y),fmaxf(a0_.z,a0_.w)),           \
                   fmaxf(fmaxf(fmaxf(a1_.x,a1_.y),fmaxf(a1_.z,a1_.w)),           \
                   fmaxf(fmaxf(fmaxf(a2_.x,a2_.y),fmaxf(a2_.z,a2_.w)),           \
                   fmaxf(fmaxf(fmaxf(a3_.x,a3_.y),fmaxf(a3_.z,a3_.w)), a16_)))); \
        r_ = 1.0f / M_;                                                          \
        Z += __logf(M_);                                                         \
    }                                                                            \
    float mtf_ = (float)(MI);                                                    \
    float wn_ = s_ * __expf(LG);                                                 \
    float wsel_ = ((MI) != 0) ? wn_ : w;                                         \
    w = wsel_ * r_;                                                              \
    float gate_ = ((tt) < S_ - 1) ? mtf_ : 0.0f;                                 \
    acc_emit = fmaf((j == (TG)) ? gate_ : 0.0f, (LG), acc_emit);                 \
    acc_tr = fmaf(tlds[ptag * T_ + (TG)], mtf_, acc_tr);                         \
    ptag = (TG);                                                                 \
    msum += (MI);                                                                \
    __builtin_amdgcn_wave_barrier();                                             \
    wbuf[g][j] = w;                                                              \
    __builtin_amdgcn_wave_barrier();                                             \
} while (0)

#define UNPACK8(dst, q0, q1) do { dst[0]=(q0).x; dst[1]=(q0).y; dst[2]=(q0).z; dst[3]=(q0).w; \
                                  dst[4]=(q1).x; dst[5]=(q1).y; dst[6]=(q1).z; dst[7]=(q1).w; } while (0)

__global__ __launch_bounds__(64) void crf_main(
    const float* __restrict__ inputs,   // [B,S,T]
    const int*   __restrict__ tags,     // [B,S]
    const int*   __restrict__ mask,     // [B,S]
    const float* __restrict__ trans,    // [T,T]
    const float* __restrict__ startt,   // [T]
    const float* __restrict__ endt,     // [T]
    float* __restrict__ partial)        // [B]
{
    __shared__ float tlds[T_ * T_];
    __shared__ __align__(16) float wbuf[4][20];   // stride 20 words: groups on disjoint banks

    const int lane = (int)threadIdx.x;
    const int g = lane / T_;              // 0..3 (3 = idle lanes 51..63)
    const int j = lane - g * T_;          // 0..16
    const int braw = (int)blockIdx.x * 3 + g;
    const bool valid = (g < 3) && (braw < B_);
    const int bsafe = (int)blockIdx.x * 3;         // always < B_
    const int b = valid ? braw : bsafe;            // idle lanes mirror group 0 (L1-hot)

    for (int k = lane; k < T_ * T_; k += 64) tlds[k] = trans[k];
    __syncthreads();

    // lane j holds column j of E = exp(transitions)
    float Ec[T_];
#pragma unroll
    for (int i = 0; i < T_; ++i) Ec[i] = __expf(tlds[i * T_ + j]);

    const float* ip  = inputs + (size_t)b * (S_ * T_) + j;
    const int4* tp4 = (const int4*)(tags + (size_t)b * S_);
    const int4* mp4 = (const int4*)(mask + (size_t)b * S_);

    // ---- block 0 loads (t = 0..7) ----
    float lgA[8], lgB[8];
#pragma unroll
    for (int u = 0; u < 8; ++u) lgA[u] = ip[u * T_];
    int4 ta0 = tp4[0], ta1 = tp4[1];
    int4 ma0 = mp4[0], ma1 = mp4[1];
    int tg_[8], mi_[8];
    UNPACK8(tg_, ta0, ta1);
    UNPACK8(mi_, ma0, ma1);

    const float stj = startt[j];
    const float enj = endt[j];

    // ---- t = 0 init ----
    float w = __expf(lgA[0] + stj);
    int ptag = tg_[0];
    float acc_emit = (j == ptag) ? lgA[0] * (float)mi_[0] : 0.0f;
    float acc_tr = 0.0f;
    float Z = 0.0f;
    int msum = mi_[0];

    __builtin_amdgcn_wave_barrier();
    wbuf[g][j] = w;
    __builtin_amdgcn_wave_barrier();

    // ---- prefetch block 1 (t = 8..15) ----
#pragma unroll
    for (int u = 0; u < 8; ++u) lgB[u] = ip[(8 + u) * T_];
    int4 tb0 = tp4[2], tb1 = tp4[3];
    int4 mb0 = mp4[2], mb1 = mp4[3];

    // ---- steps 1..7 ----
    CRF_STEP(1, 1, lgA[1], tg_[1], mi_[1]);
    CRF_STEP(2, 2, lgA[2], tg_[2], mi_[2]);
    CRF_STEP(3, 3, lgA[3], tg_[3], mi_[3]);
    CRF_STEP(4, 4, lgA[4], tg_[4], mi_[4]);
    CRF_STEP(5, 5, lgA[5], tg_[5], mi_[5]);
    CRF_STEP(6, 6, lgA[6], tg_[6], mi_[6]);
    CRF_STEP(7, 7, lgA[7], tg_[7], mi_[7]);

    // ---- main loop: blocks c = 1..63 (t = 8c .. 8c+7) ----
    for (int c = 1; c < 64; ++c) {
#pragma unroll
        for (int u = 0; u < 8; ++u) lgA[u] = lgB[u];
        ta0 = tb0; ta1 = tb1; ma0 = mb0; ma1 = mb1;
        UNPACK8(tg_, ta0, ta1);
        UNPACK8(mi_, ma0, ma1);
        if (c < 63) {
#pragma unroll
            for (int u = 0; u < 8; ++u) lgB[u] = ip[(8 * (c + 1) + u) * T_];
            tb0 = tp4[2 * (c + 1)]; tb1 = tp4[2 * (c + 1) + 1];
            mb0 = mp4[2 * (c + 1)]; mb1 = mp4[2 * (c + 1) + 1];
        }
        const int tbase = 8 * c;
        CRF_STEP(0, tbase + 0, lgA[0], tg_[0], mi_[0]);
        CRF_STEP(1, tbase + 1, lgA[1], tg_[1], mi_[1]);
        CRF_STEP(2, tbase + 2, lgA[2], tg_[2], mi_[2]);
        CRF_STEP(3, tbase + 3, lgA[3], tg_[3], mi_[3]);
        CRF_STEP(4, tbase + 4, lgA[4], tg_[4], mi_[4]);
        CRF_STEP(5, tbase + 5, lgA[5], tg_[5], mi_[5]);
        CRF_STEP(6, tbase + 6, lgA[6], tg_[6], mi_[6]);
        CRF_STEP(7, tbase + 7, lgA[7], tg_[7], mi_[7]);
    }

    // ---- denominator: Z + log(sum_j w_j * exp(end_j)) ----
    float ve = w * __expf(enj);
    __builtin_amdgcn_wave_barrier();
    wbuf[g][j] = ve;
    __builtin_amdgcn_wave_barrier();
    const float4* wv = (const float4*)(&wbuf[g][0]);
    float4 d0 = wv[0], d1 = wv[1], d2 = wv[2], d3 = wv[3];
    float d16 = wbuf[g][16];
    float dsum = ((d0.x + d0.y) + (d0.z + d0.w)) + ((d1.x + d1.y) + (d1.z + d1.w))
               + ((d2.x + d2.y) + (d2.z + d2.w)) + ((d3.x + d3.y) + (d3.z + d3.w)) + d16;
    float denom = Z + __logf(dsum);

    // ---- emission-score lane reduction ----
    __builtin_amdgcn_wave_barrier();
    wbuf[g][j] = acc_emit;
    __builtin_amdgcn_wave_barrier();
    float4 e0 = wv[0], e1 = wv[1], e2 = wv[2], e3 = wv[3];
    float e16 = wbuf[g][16];
    float esum = ((e0.x + e0.y) + (e0.z + e0.w)) + ((e1.x + e1.y) + (e1.z + e1.w))
               + ((e2.x + e2.y) + (e2.z + e2.w)) + ((e3.x + e3.y) + (e3.z + e3.w)) + e16;

    if (valid && j == 0) {
        int last_idx = msum - 1;
        if (last_idx < 0) last_idx = 0;
        int last_tag = tags[(size_t)b * S_ + last_idx];
        float last_in = inputs[((size_t)b * S_ + (S_ - 1)) * T_ + last_tag];
        float mlast = (float)mask[(size_t)b * S_ + (S_ - 1)];
        int tag0 = tags[(size_t)b * S_];
        float score = startt[tag0] + acc_tr + esum + endt[last_tag] + last_in * mlast;
        partial[braw] = score - denom;
    }
}

__global__ __launch_bounds__(256) void reduce_sum(const float* __restrict__ partial,
                                                  float* __restrict__ out)
{
    __shared__ float sm[256];
    float s = 0.0f;
    for (int i = (int)threadIdx.x; i < B_; i += 256) s += partial[i];
    sm[threadIdx.x] = s;
    __syncthreads();
    for (int k = 128; k >= 1; k >>= 1) {
        if ((int)threadIdx.x < k) sm[threadIdx.x] += sm[threadIdx.x + k];
        __syncthreads();
    }
    if (threadIdx.x == 0) out[0] = sm[0];
}

extern "C" void kernel_launch(void* const* d_in, const int* in_sizes, int n_in,
                              void* d_out, int out_size, void* d_ws, size_t ws_size,
                              hipStream_t stream)
{
    const float* inputs = (const float*)d_in[0];
    const int*   tags   = (const int*)d_in[1];
    const int*   mask   = (const int*)d_in[2];
    const float* trans  = (const float*)d_in[3];
    const float* startt = (const float*)d_in[4];
    const float* endt   = (const float*)d_in[5];
    float* out = (float*)d_out;
    float* partial = (float*)d_ws;

    const int nblk = (B_ + 2) / 3;  // 683 blocks, 3 sequences per 64-thread block
    crf_main<<<nblk, 64, 0, stream>>>(inputs, tags, mask, trans, startt, endt, partial);
    reduce_sum<<<1, 256, 0, stream>>>(partial, out);
}